// Round 2
// baseline (489.939 us; speedup 1.0000x reference)
//
#include <hip/hip_runtime.h>

typedef unsigned short u16;
typedef unsigned int   u32;
typedef __bf16 bf16x8 __attribute__((ext_vector_type(8)));
typedef u16    u16x8  __attribute__((ext_vector_type(8)));
typedef float  f32x4  __attribute__((ext_vector_type(4)));

#define DI static __device__ __forceinline__

DI float b2f(u16 u){ union { u32 i; float f; } c; c.i = ((u32)u) << 16; return c.f; }
DI u16 f2b(float f){ union { float f; u32 i; } c; c.f = f; u32 i = c.i;
                     return (u16)((i + 0x7FFFu + ((i >> 16) & 1u)) >> 16); }
DI float eluf(float x){ return x > 0.f ? x : (__expf(x) - 1.f); }
DI float sigf(float x){ return 1.f / (1.f + __expf(-x)); }
DI f32x4 mfma16(bf16x8 a, bf16x8 b, f32x4 c){
  return __builtin_amdgcn_mfma_f32_16x16x32_bf16(a, b, c, 0, 0, 0);
}
// load 8 contiguous fp32, round-to-nearest-even to bf16x8
DI bf16x8 cvt8(const float* p){
  u16x8 t;
  #pragma unroll
  for (int i = 0; i < 8; i++) t[i] = f2b(p[i]);
  return __builtin_bit_cast(bf16x8, t);
}

// ---------------------------------------------------------------------------
// Transpose + fp32->bf16 convert all weights into [N][K] (k-contiguous) in ws.
// z: 0..15 v_fc1 (64x256), 16..31 v_fc2 (256x256), 32..47 v_gate (256x256),
//    48..63 v_skip (64x256), 64 w_fc1 (1024x256), 65 w_skip (1024x16)
// ---------------------------------------------------------------------------
__global__ __launch_bounds__(256) void k_transpose(
    const float* __restrict__ vfc1, const float* __restrict__ vfc2,
    const float* __restrict__ vgate, const float* __restrict__ vskip,
    const float* __restrict__ wfc1, const float* __restrict__ wskip,
    u16* __restrict__ fc1T, u16* __restrict__ fc2T,
    u16* __restrict__ gateT, u16* __restrict__ skipT,
    u16* __restrict__ W1T, u16* __restrict__ WsT)
{
  const int z = blockIdx.z;
  const float* src; u16* dst; int K, N;
  if (z < 16)      { src = vfc1 + (size_t)z * 16384;       dst = fc1T + (size_t)z * 16384;       K = 64;   N = 256; }
  else if (z < 32) { src = vfc2 + (size_t)(z-16) * 65536;  dst = fc2T + (size_t)(z-16) * 65536;  K = 256;  N = 256; }
  else if (z < 48) { src = vgate + (size_t)(z-32) * 65536; dst = gateT + (size_t)(z-32) * 65536; K = 256;  N = 256; }
  else if (z < 64) { src = vskip + (size_t)(z-48) * 16384; dst = skipT + (size_t)(z-48) * 16384; K = 64;   N = 256; }
  else if (z == 64){ src = wfc1;  dst = W1T; K = 1024; N = 256; }
  else             { src = wskip; dst = WsT; K = 1024; N = 16;  }

  const int n0 = blockIdx.x * 32, k0 = blockIdx.y * 32;
  if (n0 >= N || k0 >= K) return;

  __shared__ u16 tile[32][33];
  const int tx = threadIdx.x, ty = threadIdx.y;
  #pragma unroll
  for (int i = 0; i < 4; i++){
    int k = k0 + ty + i * 8, n = n0 + tx;
    if (k < K && n < N) tile[ty + i * 8][tx] = f2b(src[(size_t)k * N + n]);
  }
  __syncthreads();
  #pragma unroll
  for (int i = 0; i < 4; i++){
    int n = n0 + ty + i * 8, k = k0 + tx;
    if (n < N && k < K) dst[(size_t)n * K + k] = tile[tx][ty + i * 8];
  }
}

// ---------------------------------------------------------------------------
// Kernel 1: weight GRN -> softmax weights w [N,16] (fp32, in ws)
// 256 blocks x 64 rows, 256 threads (4 waves, wave = 16-row m-block).
// GEMM [64,1024] @ [1024, 272] (cols 0..255 = fc1 -> h, 256..271 = skip -> res)
// ---------------------------------------------------------------------------
__global__ __launch_bounds__(256) void k_weight_grn(
    const float* __restrict__ x, const u16* __restrict__ W1T, const u16* __restrict__ WsT,
    const float* __restrict__ b1, const float* __restrict__ W2, const float* __restrict__ b2,
    const float* __restrict__ Wg, const float* __restrict__ bg, const float* __restrict__ bs,
    float* __restrict__ w_out)
{
  extern __shared__ char smem[];
  u16* sX = (u16*)smem;                 // [64][40]   (32 k + 8 pad) bf16
  u16* sW = sX + 64 * 40;               // [272][40]  bf16
  u16* sH = sW + 272 * 40;              // [64][264]  bf16 h (cols 0..255)
  float* sY = (float*)(sH + 64 * 264);  // [64][16]
  float* sG = sY + 64 * 16;             // [64][16]
  float* sR = sG + 64 * 16;             // [64][16]   res (fp32)

  const int tid  = threadIdx.x;
  const int lane = tid & 63;
  const int mb   = tid >> 6;
  const int ln   = lane & 15;
  const int q    = lane >> 4;
  const int row0 = blockIdx.x * 64;

  f32x4 acc[17];
  #pragma unroll
  for (int i = 0; i < 17; i++){ acc[i][0]=0.f; acc[i][1]=0.f; acc[i][2]=0.f; acc[i][3]=0.f; }

  for (int kt = 0; kt < 32; kt++){
    const int k0 = kt * 32;
    { // stage X [64][32] fp32 -> bf16
      int r = tid >> 2, c = (tid & 3) * 8;
      const float* xp = &x[(size_t)(row0 + r) * 1024 + k0 + c];
      u16x8 t;
      #pragma unroll
      for (int i = 0; i < 8; i++) t[i] = f2b(xp[i]);
      *(uint4*)&sX[r * 40 + c] = __builtin_bit_cast(uint4, t);
    }
    #pragma unroll
    for (int i = 0; i < 5; i++){ // stage W [272][32] (already bf16 in ws)
      int cid = tid + i * 256;
      if (cid < 1088){
        int n = cid >> 2, c = (cid & 3) * 8;
        const u16* src = (n < 256) ? &W1T[(size_t)n * 1024 + k0 + c]
                                   : &WsT[(size_t)(n - 256) * 1024 + k0 + c];
        *(uint4*)&sW[n * 40 + c] = *(const uint4*)src;
      }
    }
    __syncthreads();
    bf16x8 a = *(const bf16x8*)&sX[(mb * 16 + ln) * 40 + q * 8];
    #pragma unroll
    for (int nb = 0; nb < 17; nb++){
      bf16x8 b = *(const bf16x8*)&sW[(nb * 16 + ln) * 40 + q * 8];
      acc[nb] = mfma16(a, b, acc[nb]);
    }
    __syncthreads();
  }

  // epilogue: h = elu(acc + b1) -> sH (bf16); res = acc + bs -> sR (fp32)
  #pragma unroll
  for (int nb = 0; nb < 17; nb++){
    int col = nb * 16 + ln;
    float vb = (nb < 16) ? b1[col] : bs[col - 256];
    #pragma unroll
    for (int r = 0; r < 4; r++){
      int lr = mb * 16 + q * 4 + r;
      float v = acc[nb][r] + vb;
      if (nb < 16) sH[lr * 264 + col] = f2b(eluf(v));
      else         sR[lr * 16 + (col - 256)] = v;
    }
  }
  __syncthreads();

  // y = h @ W2 + b2   (64 rows x 16 cols, K = 256) -- vector fp32
  {
    int r = tid >> 2, j0 = (tid & 3) * 4;
    float a0 = b2[j0], a1 = b2[j0 + 1], a2 = b2[j0 + 2], a3 = b2[j0 + 3];
    for (int k = 0; k < 256; k++){
      float h = b2f(sH[r * 264 + k]);
      const float* w = &W2[k * 16 + j0];
      a0 += h * w[0]; a1 += h * w[1]; a2 += h * w[2]; a3 += h * w[3];
    }
    sY[r * 16 + j0] = a0; sY[r * 16 + j0 + 1] = a1; sY[r * 16 + j0 + 2] = a2; sY[r * 16 + j0 + 3] = a3;
  }
  __syncthreads();

  // gate = sigmoid(y @ Wg + bg)
  {
    int r = tid >> 2, j0 = (tid & 3) * 4;
    float g0 = bg[j0], g1 = bg[j0 + 1], g2 = bg[j0 + 2], g3 = bg[j0 + 3];
    #pragma unroll
    for (int k = 0; k < 16; k++){
      float yv = sY[r * 16 + k];
      const float* w = &Wg[k * 16 + j0];
      g0 += yv * w[0]; g1 += yv * w[1]; g2 += yv * w[2]; g3 += yv * w[3];
    }
    sG[r * 16 + j0] = sigf(g0); sG[r * 16 + j0 + 1] = sigf(g1);
    sG[r * 16 + j0 + 2] = sigf(g2); sG[r * 16 + j0 + 3] = sigf(g3);
  }
  __syncthreads();

  // w = softmax(res + gate*y) over 16
  if (tid < 64){
    int r = tid;
    float l[16]; float m = -1e30f;
    #pragma unroll
    for (int j = 0; j < 16; j++){
      float v = sR[r * 16 + j] + sG[r * 16 + j] * sY[r * 16 + j];
      l[j] = v; m = fmaxf(m, v);
    }
    float s = 0.f;
    #pragma unroll
    for (int j = 0; j < 16; j++){ l[j] = __expf(l[j] - m); s += l[j]; }
    float inv = 1.f / s;
    #pragma unroll
    for (int j = 0; j < 16; j++) w_out[(size_t)(row0 + r) * 16 + j] = l[j] * inv;
  }
}

// ---------------------------------------------------------------------------
// Kernel 2: per-variable GRNs, fully fused; z accumulated in fp32 registers.
// 256 blocks x 64 rows, 512 threads = 8 waves; wave = (m-block 0..3, n-half 0..1)
// ---------------------------------------------------------------------------
__global__ __launch_bounds__(512) void k_var_grn(
    const float* __restrict__ x,
    const u16* __restrict__ fc1T, const u16* __restrict__ fc2T,
    const u16* __restrict__ gateT, const u16* __restrict__ skipT,
    const float* __restrict__ b1, const float* __restrict__ b2,
    const float* __restrict__ bg, const float* __restrict__ bs,
    const float* __restrict__ w_in, float* __restrict__ out)
{
  extern __shared__ char smem[];
  u16* sW  = (u16*)smem;               // [256][72] bf16 B-tiles
  u16* sH  = sW + 256 * 72;            // [64][264] bf16 hv then yv
  float* sWt = (float*)(sH + 64 * 264);// [64][16]  softmax weights fp32

  const int tid  = threadIdx.x;
  const int lane = tid & 63;
  const int wid  = tid >> 6;
  const int mb   = wid >> 1;
  const int nh   = wid & 1;
  const int ln   = lane & 15;
  const int q    = lane >> 4;
  const int row0 = blockIdx.x * 64;
  const int colbase = nh * 128;
  const int arow = mb * 16 + ln;

  // stage softmax weights (fp32, 1024 entries, 512 threads x 2)
  #pragma unroll
  for (int i = 0; i < 2; i++){
    int idx = tid + i * 512;
    int r = idx >> 4, j = idx & 15;
    sWt[idx] = w_in[(size_t)(row0 + r) * 16 + j];
  }

  f32x4 z[8];
  #pragma unroll
  for (int i = 0; i < 8; i++){ z[i][0]=0.f; z[i][1]=0.f; z[i][2]=0.f; z[i][3]=0.f; }

  for (int v = 0; v < 16; v++){
    // A-fragments for phase 1 from global x (fp32 -> bf16)
    const float* xp = &x[(size_t)(row0 + arow) * 1024 + v * 64];
    bf16x8 a0 = cvt8(xp + q * 8);
    bf16x8 a1 = cvt8(xp + 32 + q * 8);

    __syncthreads();  // prior iteration done with sW/sH (v=0: sWt visible)
    #pragma unroll
    for (int i = 0; i < 4; i++){ // stage fc1T[v] [256][64]
      int cid = tid + i * 512;
      int n = cid >> 3, c = (cid & 7) * 8;
      *(uint4*)&sW[n * 72 + c] = *(const uint4*)&fc1T[(size_t)v * 16384 + n * 64 + c];
    }
    __syncthreads();

    // phase 1a: hv = elu(Xv @ W1v + b1)
    f32x4 hacc[8];
    #pragma unroll
    for (int i = 0; i < 8; i++){ hacc[i][0]=0.f; hacc[i][1]=0.f; hacc[i][2]=0.f; hacc[i][3]=0.f; }
    #pragma unroll
    for (int nb = 0; nb < 8; nb++){
      bf16x8 bb0 = *(const bf16x8*)&sW[(colbase + nb * 16 + ln) * 72 + q * 8];
      hacc[nb] = mfma16(a0, bb0, hacc[nb]);
      bf16x8 bb1 = *(const bf16x8*)&sW[(colbase + nb * 16 + ln) * 72 + 32 + q * 8];
      hacc[nb] = mfma16(a1, bb1, hacc[nb]);
    }
    #pragma unroll
    for (int nb = 0; nb < 8; nb++){
      int col = colbase + nb * 16 + ln;
      float vb = b1[v * 256 + col];
      #pragma unroll
      for (int r = 0; r < 4; r++){
        int lr = mb * 16 + q * 4 + r;
        sH[lr * 264 + col] = f2b(eluf(hacc[nb][r] + vb));
      }
    }
    __syncthreads();  // everyone done reading sW (fc1)

    #pragma unroll
    for (int i = 0; i < 4; i++){ // stage skipT[v] [256][64]
      int cid = tid + i * 512;
      int n = cid >> 3, c = (cid & 7) * 8;
      *(uint4*)&sW[n * 72 + c] = *(const uint4*)&skipT[(size_t)v * 16384 + n * 64 + c];
    }
    __syncthreads();

    float wv[4];
    #pragma unroll
    for (int r = 0; r < 4; r++) wv[r] = sWt[(mb * 16 + q * 4 + r) * 16 + v];

    // phase 1b: rv = Xv @ Wsv + bs ; z += wv * rv
    {
      f32x4 racc[8];
      #pragma unroll
      for (int i = 0; i < 8; i++){ racc[i][0]=0.f; racc[i][1]=0.f; racc[i][2]=0.f; racc[i][3]=0.f; }
      #pragma unroll
      for (int nb = 0; nb < 8; nb++){
        bf16x8 bb0 = *(const bf16x8*)&sW[(colbase + nb * 16 + ln) * 72 + q * 8];
        racc[nb] = mfma16(a0, bb0, racc[nb]);
        bf16x8 bb1 = *(const bf16x8*)&sW[(colbase + nb * 16 + ln) * 72 + 32 + q * 8];
        racc[nb] = mfma16(a1, bb1, racc[nb]);
      }
      #pragma unroll
      for (int nb = 0; nb < 8; nb++){
        int col = colbase + nb * 16 + ln;
        float vb = bs[v * 256 + col];
        #pragma unroll
        for (int r = 0; r < 4; r++) z[nb][r] += wv[r] * (racc[nb][r] + vb);
      }
    }

    // phase 2: yv = hv @ W2v + b2   (K = 256, 4 chunks of 64)
    f32x4 yacc[8];
    #pragma unroll
    for (int i = 0; i < 8; i++){ yacc[i][0]=0.f; yacc[i][1]=0.f; yacc[i][2]=0.f; yacc[i][3]=0.f; }
    for (int kc = 0; kc < 4; kc++){
      __syncthreads();  // prior readers of sW done
      #pragma unroll
      for (int i = 0; i < 4; i++){
        int cid = tid + i * 512;
        int n = cid >> 3, c = (cid & 7) * 8;
        *(uint4*)&sW[n * 72 + c] = *(const uint4*)&fc2T[(size_t)v * 65536 + (size_t)n * 256 + kc * 64 + c];
      }
      __syncthreads();
      #pragma unroll
      for (int ks = 0; ks < 2; ks++){
        bf16x8 ah = *(const bf16x8*)&sH[arow * 264 + kc * 64 + ks * 32 + q * 8];
        #pragma unroll
        for (int nb = 0; nb < 8; nb++){
          bf16x8 bb = *(const bf16x8*)&sW[(colbase + nb * 16 + ln) * 72 + ks * 32 + q * 8];
          yacc[nb] = mfma16(ah, bb, yacc[nb]);
        }
      }
    }
    __syncthreads();  // all phase-2 reads of sH (hv) and sW done

    // yv: add bias, save fp32, write bf16 into sH (replacing hv)
    f32x4 ysave[8];
    #pragma unroll
    for (int nb = 0; nb < 8; nb++){
      int col = colbase + nb * 16 + ln;
      float vb = b2[v * 256 + col];
      #pragma unroll
      for (int r = 0; r < 4; r++){
        int lr = mb * 16 + q * 4 + r;
        float yy = yacc[nb][r] + vb;
        ysave[nb][r] = yy;
        sH[lr * 264 + col] = f2b(yy);
      }
    }
    // stage gate chunk 0 (different LDS region than the sH writes above)
    #pragma unroll
    for (int i = 0; i < 4; i++){
      int cid = tid + i * 512;
      int n = cid >> 3, c = (cid & 7) * 8;
      *(uint4*)&sW[n * 72 + c] = *(const uint4*)&gateT[(size_t)v * 65536 + (size_t)n * 256 + 0 * 64 + c];
    }
    __syncthreads();

    // phase 3: gv = sigmoid(yv @ Wgv + bg)
    f32x4 gacc[8];
    #pragma unroll
    for (int i = 0; i < 8; i++){ gacc[i][0]=0.f; gacc[i][1]=0.f; gacc[i][2]=0.f; gacc[i][3]=0.f; }
    for (int kc = 0; kc < 4; kc++){
      if (kc > 0){
        __syncthreads();
        #pragma unroll
        for (int i = 0; i < 4; i++){
          int cid = tid + i * 512;
          int n = cid >> 3, c = (cid & 7) * 8;
          *(uint4*)&sW[n * 72 + c] = *(const uint4*)&gateT[(size_t)v * 65536 + (size_t)n * 256 + kc * 64 + c];
        }
        __syncthreads();
      }
      #pragma unroll
      for (int ks = 0; ks < 2; ks++){
        bf16x8 ah = *(const bf16x8*)&sH[arow * 264 + kc * 64 + ks * 32 + q * 8];
        #pragma unroll
        for (int nb = 0; nb < 8; nb++){
          bf16x8 bb = *(const bf16x8*)&sW[(colbase + nb * 16 + ln) * 72 + ks * 32 + q * 8];
          gacc[nb] = mfma16(ah, bb, gacc[nb]);
        }
      }
    }

    // z += wv * sigmoid(gacc + bg) * yv
    #pragma unroll
    for (int nb = 0; nb < 8; nb++){
      int col = colbase + nb * 16 + ln;
      float vb = bg[v * 256 + col];
      #pragma unroll
      for (int r = 0; r < 4; r++)
        z[nb][r] += wv[r] * sigf(gacc[nb][r] + vb) * ysave[nb][r];
    }
  }

  // store z -> out (fp32), C/D layout: row = q*4+reg, col = lane&15
  #pragma unroll
  for (int nb = 0; nb < 8; nb++){
    int col = colbase + nb * 16 + ln;
    #pragma unroll
    for (int r = 0; r < 4; r++){
      int row = row0 + mb * 16 + q * 4 + r;
      out[(size_t)row * 256 + col] = z[nb][r];
    }
  }
}

// ---------------------------------------------------------------------------
extern "C" void kernel_launch(void* const* d_in, const int* in_sizes, int n_in,
                              void* d_out, int out_size, void* d_ws, size_t ws_size,
                              hipStream_t stream)
{
  const float* x     = (const float*)d_in[0];
  const float* wfc1w = (const float*)d_in[1];
  const float* wfc1b = (const float*)d_in[2];
  const float* wfc2w = (const float*)d_in[3];
  const float* wfc2b = (const float*)d_in[4];
  const float* wgw   = (const float*)d_in[5];
  const float* wgb   = (const float*)d_in[6];
  const float* wsw   = (const float*)d_in[7];
  const float* wsb   = (const float*)d_in[8];
  const float* vfc1w = (const float*)d_in[9];
  const float* vfc1b = (const float*)d_in[10];
  const float* vfc2w = (const float*)d_in[11];
  const float* vfc2b = (const float*)d_in[12];
  const float* vgw   = (const float*)d_in[13];
  const float* vgb   = (const float*)d_in[14];
  const float* vsw   = (const float*)d_in[15];
  const float* vsb   = (const float*)d_in[16];

  u16* ws    = (u16*)d_ws;
  u16* fc1T  = ws;                     // 16*256*64   = 262144 elems (bf16)
  u16* fc2T  = fc1T + 262144;          // 16*256*256  = 1048576
  u16* gateT = fc2T + 1048576;         // 1048576
  u16* skipT = gateT + 1048576;        // 262144
  u16* W1T   = skipT + 262144;         // 256*1024    = 262144
  u16* WsT   = W1T + 262144;           // 16*1024     = 16384
  float* w_ws = (float*)(WsT + 16384); // 16384*16 fp32

  k_transpose<<<dim3(8, 32, 66), dim3(32, 8, 1), 0, stream>>>(
      vfc1w, vfc2w, vgw, vsw, wfc1w, wsw, fc1T, fc2T, gateT, skipT, W1T, WsT);

  size_t sm1 = (size_t)(64 * 40 + 272 * 40 + 64 * 264) * 2 + (size_t)(64 * 16) * 4 * 3; // 72960 B
  k_weight_grn<<<dim3(256), dim3(256), sm1, stream>>>(
      x, W1T, WsT, wfc1b, wfc2w, wfc2b, wgw, wgb, wsb, w_ws);

  size_t sm2 = (size_t)(256 * 72 + 64 * 264) * 2 + (size_t)(64 * 16) * 4; // 74752 B
  k_var_grn<<<dim3(256), dim3(512), sm2, stream>>>(
      x, fc1T, fc2T, gateT, skipT, vfc1b, vfc2b, vgb, vsb, w_ws, (float*)d_out);
}